// Round 4
// baseline (209.621 us; speedup 1.0000x reference)
//
#include <hip/hip_runtime.h>
#include <hip/hip_bf16.h>

#define HW 36864  // 192*192

typedef __attribute__((ext_vector_type(8))) short short8;   // 8 x bf16 (4 VGPR)
typedef __attribute__((ext_vector_type(16))) float f32x16;  // 32x32 MFMA C/D

__device__ __forceinline__ unsigned short f2bf(float f) {
    unsigned u = __float_as_uint(f);
    u += 0x7fffu + ((u >> 16) & 1u);   // RNE
    return (unsigned short)(u >> 16);
}
__device__ __forceinline__ unsigned pk2(float lo, float hi) {
    unsigned r;
    asm("v_cvt_pk_bf16_f32 %0, %1, %2" : "=v"(r) : "v"(lo), "v"(hi));
    return r;
}
__device__ __forceinline__ void plswap(unsigned &a, unsigned &b) {
    asm volatile("v_permlane32_swap_b32 %0, %1" : "+v"(a), "+v"(b));
}

union FragW { unsigned u[4]; short8 s; };

// d_ws layout (bf16):
//   Qw  [512][576][16]  at 0          (9 437 184 B)   rec = (win*576+m)*32 B
//   Kw  [512][576][16]  at 9437184    (9 437 184 B)   same record layout (K^T)
//   Vw  [512][64][576]  at 18874368   (37 748 736 B)  byte = win*73728 + ch*1152 + 2m
#define QW_OFF 0
#define KW_OFF 9437184
#define VW_OFF 18874368

// ---------------- Block 1: 4x4 window attention, MFMA (unchanged) ------------
__global__ __launch_bounds__(256) void attn1_mfma(
    const float* __restrict__ x,
    const float* __restrict__ wq, const float* __restrict__ bq,
    const float* __restrict__ wk, const float* __restrict__ bk,
    const float* __restrict__ wv, const float* __restrict__ bv,
    const float* __restrict__ gamma, float* __restrict__ out)
{
    __shared__ char smem[4 * 8192];

    const int tid   = threadIdx.x;
    const int wv_id = tid >> 6;
    const int lane  = tid & 63;
    const int l32   = lane & 31;
    const int h     = lane >> 5;
    char* VsW = smem + wv_id * 8192;

    const int gw0 = blockIdx.x * 16 + wv_id * 4;

    f32x16 zf;
    #pragma unroll
    for (int r = 0; r < 16; ++r) zf[r] = 0.f;

    FragW wqkf[4], wvf[2][4];
    {
        const float* wrow = (l32 < 16) ? (wq + l32 * 64) : (wk + (l32 - 16) * 64);
        #pragma unroll
        for (int cc = 0; cc < 4; ++cc)
            #pragma unroll
            for (int j = 0; j < 4; ++j) {
                const int c = cc * 16 + 8 * h + 2 * j;
                wqkf[cc].u[j] = pk2(wrow[c], wrow[c + 1]);
            }
        #pragma unroll
        for (int ot = 0; ot < 2; ++ot) {
            const float* wvr = wv + (size_t)(ot * 32 + l32) * 64;
            #pragma unroll
            for (int cc = 0; cc < 4; ++cc)
                #pragma unroll
                for (int j = 0; j < 4; ++j) {
                    const int c = cc * 16 + 8 * h + 2 * j;
                    wvf[ot][cc].u[j] = pk2(wvr[c], wvr[c + 1]);
                }
        }
    }
    float bqv[8], bkv[8], bvv[2][16];
    #pragma unroll
    for (int r = 0; r < 8; ++r) {
        const int c = (r & 3) + 8 * (r >> 2) + 4 * h;
        bqv[r] = bq[c];
        bkv[r] = bk[c];
    }
    #pragma unroll
    for (int ot = 0; ot < 2; ++ot)
        #pragma unroll
        for (int r = 0; r < 16; ++r)
            bvv[ot][r] = bv[ot * 32 + (r & 3) + 8 * (r >> 2) + 4 * h];

    size_t gbt[2];
    #pragma unroll
    for (int t = 0; t < 2; ++t) {
        const int gwin = gw0 + 2 * t + (l32 >> 4);
        const int b = gwin / 2304;
        const int rem = gwin % 2304;
        const int Y = rem / 48, X = rem % 48;
        gbt[t] = (size_t)b * 64 * HW + (size_t)(Y * 4 + ((l32 >> 2) & 3)) * 192
               + (X * 4 + (l32 & 3));
    }

    FragW qf[2], kf[2];
    #pragma unroll
    for (int t = 0; t < 2; ++t) {
        const size_t gb = gbt[t];
        FragW xw[4];
        #pragma unroll
        for (int cc = 0; cc < 4; ++cc)
            #pragma unroll
            for (int j = 0; j < 4; ++j) {
                const int c = cc * 16 + 8 * h + 2 * j;
                xw[cc].u[j] = pk2(x[gb + (size_t)c * HW], x[gb + (size_t)(c + 1) * HW]);
            }

        f32x16 dqk = zf;
        #pragma unroll
        for (int cc = 0; cc < 4; ++cc)
            dqk = __builtin_amdgcn_mfma_f32_32x32x16_bf16(wqkf[cc].s, xw[cc].s, dqk, 0, 0, 0);

        {
            float q0[8];
            #pragma unroll
            for (int r = 0; r < 8; ++r) q0[r] = dqk[r] + bqv[r];
            unsigned A0 = pk2(q0[0], q0[1]), B0 = pk2(q0[2], q0[3]);
            unsigned C0 = pk2(q0[4], q0[5]), D0 = pk2(q0[6], q0[7]);
            plswap(A0, C0); plswap(B0, D0);
            qf[t].u[0] = A0; qf[t].u[1] = B0; qf[t].u[2] = C0; qf[t].u[3] = D0;
        }
        {
            float k0[8];
            #pragma unroll
            for (int r = 0; r < 8; ++r) k0[r] = dqk[8 + r] + bkv[r];
            unsigned A0 = pk2(k0[0], k0[1]), B0 = pk2(k0[2], k0[3]);
            unsigned C0 = pk2(k0[4], k0[5]), D0 = pk2(k0[6], k0[7]);
            plswap(A0, C0); plswap(B0, D0);
            kf[t].u[0] = A0; kf[t].u[1] = B0; kf[t].u[2] = C0; kf[t].u[3] = D0;
        }

        #pragma unroll
        for (int ot = 0; ot < 2; ++ot) {
            f32x16 dv = zf;
            #pragma unroll
            for (int cc = 0; cc < 4; ++cc)
                dv = __builtin_amdgcn_mfma_f32_32x32x16_bf16(wvf[ot][cc].s, xw[cc].s, dv, 0, 0, 0);
            #pragma unroll
            for (int r = 0; r < 16; ++r) {
                const int ch = ot * 32 + (r & 3) + 8 * (r >> 2) + 4 * h;
                *(unsigned short*)(VsW + ((ch * 128 + 2 * (t * 32 + l32)) ^ ((ch & 7) << 4)))
                    = f2bf(dv[r] + bvv[ot][r]);
            }
        }
    }
    __syncthreads();

    const float g = gamma[0];
    const bool wa = (l32 < 16);

    #pragma unroll
    for (int t = 0; t < 2; ++t) {
        f32x16 sT = __builtin_amdgcn_mfma_f32_32x32x16_bf16(kf[t].s, qf[t].s, zf, 0, 0, 0);

        float e[8];
        #pragma unroll
        for (int j = 0; j < 8; ++j) e[j] = __expf(wa ? sT[j] : sT[8 + j]);
        float ls = ((e[0] + e[1]) + (e[2] + e[3])) + ((e[4] + e[5]) + (e[6] + e[7]));
        ls += __shfl_xor(ls, 32);

        unsigned A0 = pk2(e[0], e[1]), B0 = pk2(e[2], e[3]);
        unsigned C0 = pk2(e[4], e[5]), D0 = pk2(e[6], e[7]);
        plswap(A0, C0); plswap(B0, D0);
        FragW pa, pb;
        pa.u[0] = wa ? A0 : 0u; pa.u[1] = wa ? B0 : 0u;
        pa.u[2] = wa ? C0 : 0u; pa.u[3] = wa ? D0 : 0u;
        pb.u[0] = wa ? 0u : A0; pb.u[1] = wa ? 0u : B0;
        pb.u[2] = wa ? 0u : C0; pb.u[3] = wa ? 0u : D0;

        f32x16 acc0 = zf, acc1 = zf;
        #pragma unroll
        for (int ws = 0; ws < 2; ++ws) {
            const short8 pfrag = ws ? pb.s : pa.s;
            const int mbase = t * 64 + ws * 32 + 16 * h;
            const int ch0 = l32, ch1 = 32 + l32;
            const short8 v0 = *(const short8*)(VsW + ((ch0 * 128 + mbase) ^ ((ch0 & 7) << 4)));
            const short8 v1 = *(const short8*)(VsW + ((ch1 * 128 + mbase) ^ ((ch1 & 7) << 4)));
            acc0 = __builtin_amdgcn_mfma_f32_32x32x16_bf16(v0, pfrag, acc0, 0, 0, 0);
            acc1 = __builtin_amdgcn_mfma_f32_32x32x16_bf16(v1, pfrag, acc1, 0, 0, 0);
        }

        const float inv = 1.f / ls;
        const size_t gb = gbt[t];
        #pragma unroll
        for (int r = 0; r < 16; ++r) {
            const int cA = (r & 3) + 8 * (r >> 2) + 4 * h;
            const int cB = 32 + cA;
            const size_t iA = gb + (size_t)cA * HW;
            const size_t iB = gb + (size_t)cB * HW;
            out[iA] = fmaf(g, acc0[r] * inv, x[iA]);
            out[iB] = fmaf(g, acc1[r] * inv, x[iB]);
        }
    }
}

// ---------------- proj2: QKV projection for block 2, coalesced ---------------
// Block = one image row (b, y): 192 threads = 3 waves x 2 tiles x 32 px.
__global__ __launch_bounds__(192) void proj2_kernel(
    const float* __restrict__ io,
    const float* __restrict__ wq, const float* __restrict__ bq,
    const float* __restrict__ wk, const float* __restrict__ bk,
    const float* __restrict__ wv, const float* __restrict__ bv,
    char* __restrict__ ws)
{
    const int bid = blockIdx.x;
    const int b = bid / 192, y = bid % 192;
    const int tid = threadIdx.x;
    const int wv_id = tid >> 6;
    const int l32 = tid & 31;
    const int h = (tid >> 5) & 1;
    const size_t rowbase = (size_t)b * 64 * HW + (size_t)y * 192;

    f32x16 zf;
    #pragma unroll
    for (int r = 0; r < 16; ++r) zf[r] = 0.f;

    FragW wqkf[4], wvf[2][4];
    {
        const float* wrow = (l32 < 16) ? (wq + l32 * 64) : (wk + (l32 - 16) * 64);
        #pragma unroll
        for (int cc = 0; cc < 4; ++cc)
            #pragma unroll
            for (int j = 0; j < 4; ++j) {
                const int c = cc * 16 + 8 * h + 2 * j;
                wqkf[cc].u[j] = pk2(wrow[c], wrow[c + 1]);
            }
        #pragma unroll
        for (int ot = 0; ot < 2; ++ot) {
            const float* wvr = wv + (size_t)(ot * 32 + l32) * 64;
            #pragma unroll
            for (int cc = 0; cc < 4; ++cc)
                #pragma unroll
                for (int j = 0; j < 4; ++j) {
                    const int c = cc * 16 + 8 * h + 2 * j;
                    wvf[ot][cc].u[j] = pk2(wvr[c], wvr[c + 1]);
                }
        }
    }
    float bias_qk[16], bvv[2][16];
    #pragma unroll
    for (int r = 0; r < 8; ++r) {
        const int c = (r & 3) + 8 * (r >> 2) + 4 * h;
        bias_qk[r] = bq[c];
        bias_qk[8 + r] = bk[c];
    }
    #pragma unroll
    for (int ot = 0; ot < 2; ++ot)
        #pragma unroll
        for (int r = 0; r < 16; ++r)
            bvv[ot][r] = bv[ot * 32 + (r & 3) + 8 * (r >> 2) + 4 * h];

    char* Qw = ws + QW_OFF;
    char* Kw = ws + KW_OFF;
    char* Vw = ws + VW_OFF;

    #pragma unroll
    for (int t = 0; t < 2; ++t) {
        const int xx = wv_id * 64 + t * 32 + l32;

        FragW xw[4];
        #pragma unroll
        for (int cc = 0; cc < 4; ++cc)
            #pragma unroll
            for (int j = 0; j < 4; ++j) {
                const int c = cc * 16 + 8 * h + 2 * j;
                xw[cc].u[j] = pk2(io[rowbase + (size_t)c * HW + xx],
                                  io[rowbase + (size_t)(c + 1) * HW + xx]);
            }

        f32x16 dqk = zf;
        #pragma unroll
        for (int cc = 0; cc < 4; ++cc)
            dqk = __builtin_amdgcn_mfma_f32_32x32x16_bf16(wqkf[cc].s, xw[cc].s, dqk, 0, 0, 0);

        const int win = b * 64 + (xx & 7) * 8 + (y & 7);
        const int m = (y >> 3) * 24 + (xx >> 3);
        const size_t rec = (size_t)(win * 576 + m) * 32;

        #pragma unroll
        for (int k = 0; k < 2; ++k) {
            // Q rows (regs 0..7)
            unsigned u0 = pk2(dqk[4 * k] + bias_qk[4 * k], dqk[4 * k + 1] + bias_qk[4 * k + 1]);
            unsigned u1 = pk2(dqk[4 * k + 2] + bias_qk[4 * k + 2], dqk[4 * k + 3] + bias_qk[4 * k + 3]);
            *(unsigned*)(Qw + rec + 8 * h + 16 * k) = u0;
            *(unsigned*)(Qw + rec + 8 * h + 16 * k + 4) = u1;
            // K rows (regs 8..15)
            const int r8 = 8 + 4 * k;
            unsigned w0 = pk2(dqk[r8] + bias_qk[r8], dqk[r8 + 1] + bias_qk[r8 + 1]);
            unsigned w1 = pk2(dqk[r8 + 2] + bias_qk[r8 + 2], dqk[r8 + 3] + bias_qk[r8 + 3]);
            *(unsigned*)(Kw + rec + 8 * h + 16 * k) = w0;
            *(unsigned*)(Kw + rec + 8 * h + 16 * k + 4) = w1;
        }

        #pragma unroll
        for (int ot = 0; ot < 2; ++ot) {
            f32x16 dv = zf;
            #pragma unroll
            for (int cc = 0; cc < 4; ++cc)
                dv = __builtin_amdgcn_mfma_f32_32x32x16_bf16(wvf[ot][cc].s, xw[cc].s, dv, 0, 0, 0);
            #pragma unroll
            for (int r = 0; r < 16; ++r) {
                const int ch = ot * 32 + (r & 3) + 8 * (r >> 2) + 4 * h;
                *(unsigned short*)(Vw + (size_t)win * 73728 + ch * 1152 + 2 * m)
                    = f2bf(dv[r] + bvv[ot][r]);
            }
        }
    }
}

// ---------------- attn2c: 8x8 chess attention consumer ----------------------
// One block per window (win = blockIdx.x), 576 threads = 9 waves.
// Q/K frags read coalesced from d_ws; V bulk-copied into swizzled LDS.
__global__ __launch_bounds__(576, 2) void attn2c_kernel(
    float* io, const char* __restrict__ ws, const float* __restrict__ gamma)
{
    extern __shared__ char smem[];   // Vs swizzled, 73728 B

    const int wid = blockIdx.x;
    const int b  = wid >> 6;
    const int a  = wid & 7;
    const int c0 = (wid >> 3) & 7;

    const int tid = threadIdx.x;
    const int wv_id = tid >> 6;
    const int l32 = tid & 31;
    const int h   = (tid >> 5) & 1;
    const int n0  = wv_id * 64;
    const size_t bbase = (size_t)b * 64 * HW;

    const char* Qw = ws + QW_OFF + (size_t)wid * 18432;
    const char* Kw = ws + KW_OFF + (size_t)wid * 18432;
    const char* Vw = ws + VW_OFF + (size_t)wid * 73728;

    // V: coalesced global read -> swizzled LDS write (8 passes x 9216 B)
    #pragma unroll
    for (int p = 0; p < 8; ++p) {
        const int off = p * 9216 + tid * 16;
        const int chrow = tid / 72;                  // == ch & 7 for this pass
        const short8 v = *(const short8*)(Vw + off);
        *(short8*)(smem + (off ^ (chrow << 4))) = v;
    }

    // Q fragments (coalesced 16B/lane)
    const short8 qf0 = *(const short8*)(Qw + (n0 + l32) * 32 + 16 * h);
    const short8 qf1 = *(const short8*)(Qw + (n0 + 32 + l32) * 32 + 16 * h);

    f32x16 zf;
    #pragma unroll
    for (int r = 0; r < 16; ++r) zf[r] = 0.f;

    __syncthreads();

    f32x16 accA = zf, accB = zf, accC = zf, accD = zf;
    float ls0 = 0.f, ls1 = 0.f;
    const int chA = l32, chB = 32 + l32;
    const int swzA = (chA & 7) << 4, swzB = (chB & 7) << 4;

    short8 kf = *(const short8*)(Kw + l32 * 32 + 16 * h);

    #pragma unroll 1
    for (int mt = 0; mt < 18; ++mt) {
        const int m0 = mt * 32;
        f32x16 s0 = __builtin_amdgcn_mfma_f32_32x32x16_bf16(kf, qf0, zf, 0, 0, 0);
        f32x16 s1 = __builtin_amdgcn_mfma_f32_32x32x16_bf16(kf, qf1, zf, 0, 0, 0);

        short8 kfn = kf;
        if (mt < 17) kfn = *(const short8*)(Kw + (m0 + 32 + l32) * 32 + 16 * h);

        const short8 vA0 = *(const short8*)(smem + ((chA * 1152 + 2 * (m0 + 8 * h)) ^ swzA));
        const short8 vA1 = *(const short8*)(smem + ((chA * 1152 + 2 * (m0 + 16 + 8 * h)) ^ swzA));
        const short8 vB0 = *(const short8*)(smem + ((chB * 1152 + 2 * (m0 + 8 * h)) ^ swzB));
        const short8 vB1 = *(const short8*)(smem + ((chB * 1152 + 2 * (m0 + 16 + 8 * h)) ^ swzB));

        #pragma unroll
        for (int r = 0; r < 16; ++r) s0[r] = __expf(s0[r]);
        #pragma unroll
        for (int r = 0; r < 16; ++r) s1[r] = __expf(s1[r]);
        ls0 += ((s0[0]+s0[1])+(s0[2]+s0[3])) + ((s0[4]+s0[5])+(s0[6]+s0[7]))
             + ((s0[8]+s0[9])+(s0[10]+s0[11])) + ((s0[12]+s0[13])+(s0[14]+s0[15]));
        ls1 += ((s1[0]+s1[1])+(s1[2]+s1[3])) + ((s1[4]+s1[5])+(s1[6]+s1[7]))
             + ((s1[8]+s1[9])+(s1[10]+s1[11])) + ((s1[12]+s1[13])+(s1[14]+s1[15]));

        FragW pf00, pf01, pf10, pf11;
        {
            unsigned A0 = pk2(s0[0], s0[1]), B0 = pk2(s0[2], s0[3]);
            unsigned C0 = pk2(s0[4], s0[5]), D0 = pk2(s0[6], s0[7]);
            plswap(A0, C0); plswap(B0, D0);
            pf00.u[0] = A0; pf00.u[1] = B0; pf00.u[2] = C0; pf00.u[3] = D0;
            unsigned E0 = pk2(s0[8], s0[9]),  F0 = pk2(s0[10], s0[11]);
            unsigned G0 = pk2(s0[12], s0[13]), H0 = pk2(s0[14], s0[15]);
            plswap(E0, G0); plswap(F0, H0);
            pf01.u[0] = E0; pf01.u[1] = F0; pf01.u[2] = G0; pf01.u[3] = H0;
            unsigned A1 = pk2(s1[0], s1[1]), B1 = pk2(s1[2], s1[3]);
            unsigned C1 = pk2(s1[4], s1[5]), D1 = pk2(s1[6], s1[7]);
            plswap(A1, C1); plswap(B1, D1);
            pf10.u[0] = A1; pf10.u[1] = B1; pf10.u[2] = C1; pf10.u[3] = D1;
            unsigned E1 = pk2(s1[8], s1[9]),  F1 = pk2(s1[10], s1[11]);
            unsigned G1 = pk2(s1[12], s1[13]), H1 = pk2(s1[14], s1[15]);
            plswap(E1, G1); plswap(F1, H1);
            pf11.u[0] = E1; pf11.u[1] = F1; pf11.u[2] = G1; pf11.u[3] = H1;
        }

        accA = __builtin_amdgcn_mfma_f32_32x32x16_bf16(vA0, pf00.s, accA, 0, 0, 0);
        accA = __builtin_amdgcn_mfma_f32_32x32x16_bf16(vA1, pf01.s, accA, 0, 0, 0);
        accB = __builtin_amdgcn_mfma_f32_32x32x16_bf16(vB0, pf00.s, accB, 0, 0, 0);
        accB = __builtin_amdgcn_mfma_f32_32x32x16_bf16(vB1, pf01.s, accB, 0, 0, 0);
        accC = __builtin_amdgcn_mfma_f32_32x32x16_bf16(vA0, pf10.s, accC, 0, 0, 0);
        accC = __builtin_amdgcn_mfma_f32_32x32x16_bf16(vA1, pf11.s, accC, 0, 0, 0);
        accD = __builtin_amdgcn_mfma_f32_32x32x16_bf16(vB0, pf10.s, accD, 0, 0, 0);
        accD = __builtin_amdgcn_mfma_f32_32x32x16_bf16(vB1, pf11.s, accD, 0, 0, 0);

        kf = kfn;
    }

    ls0 += __shfl_xor(ls0, 32);
    ls1 += __shfl_xor(ls1, 32);
    const float g = gamma[0];
    const float inv0 = 1.f / ls0, inv1 = 1.f / ls1;

    const int pn0 = n0 + l32, pn1 = n0 + 32 + l32;
    const int i0 = pn0 / 24, j0 = pn0 - i0 * 24;
    const int i1 = pn1 / 24, j1 = pn1 - i1 * 24;
    const size_t gb0 = bbase + (size_t)(a + 8 * i0) * 192 + (c0 + 8 * j0);
    const size_t gb1 = bbase + (size_t)(a + 8 * i1) * 192 + (c0 + 8 * j1);

    #pragma unroll
    for (int r = 0; r < 16; ++r) {
        const int cA = (r & 3) + 8 * (r >> 2) + 4 * h;
        const int cB = 32 + cA;
        const size_t iA0 = gb0 + (size_t)cA * HW;
        const size_t iB0 = gb0 + (size_t)cB * HW;
        const size_t iA1 = gb1 + (size_t)cA * HW;
        const size_t iB1 = gb1 + (size_t)cB * HW;
        io[iA0] = fmaf(g, accA[r] * inv0, io[iA0]);
        io[iB0] = fmaf(g, accB[r] * inv0, io[iB0]);
        io[iA1] = fmaf(g, accC[r] * inv1, io[iA1]);
        io[iB1] = fmaf(g, accD[r] * inv1, io[iB1]);
    }
}

extern "C" void kernel_launch(void* const* d_in, const int* in_sizes, int n_in,
                              void* d_out, int out_size, void* d_ws, size_t ws_size,
                              hipStream_t stream)
{
    const float* x   = (const float*)d_in[0];
    const float* wq1 = (const float*)d_in[1];
    const float* bq1 = (const float*)d_in[2];
    const float* wk1 = (const float*)d_in[3];
    const float* bk1 = (const float*)d_in[4];
    const float* wv1 = (const float*)d_in[5];
    const float* bv1 = (const float*)d_in[6];
    const float* wq2 = (const float*)d_in[7];
    const float* bq2 = (const float*)d_in[8];
    const float* wk2 = (const float*)d_in[9];
    const float* bk2 = (const float*)d_in[10];
    const float* wv2 = (const float*)d_in[11];
    const float* bv2 = (const float*)d_in[12];
    const float* g1  = (const float*)d_in[13];
    const float* g2  = (const float*)d_in[14];
    float* out = (float*)d_out;
    char* ws = (char*)d_ws;

    attn1_mfma<<<dim3(1152), dim3(256), 0, stream>>>(
        x, wq1, bq1, wk1, bk1, wv1, bv1, g1, out);

    proj2_kernel<<<dim3(1536), dim3(192), 0, stream>>>(
        out, wq2, bq2, wk2, bk2, wv2, bv2, ws);

    attn2c_kernel<<<dim3(512), dim3(576), 73728, stream>>>(
        out, ws, g2);
}